// Round 8
// baseline (536.578 us; speedup 1.0000x reference)
//
#include <hip/hip_runtime.h>

#define NN 50000
#define NE 800000
#define D 128
#define NG 128
#define POOL_NODES 128
#define SCAN_NB ((NN + 1023) / 1024)   // 49

typedef __attribute__((ext_vector_type(8))) short bf16x8;
typedef __attribute__((ext_vector_type(4))) float f32x4;

static __device__ __forceinline__ ushort f2bf(float f) {
    uint x = __float_as_uint(f);
    x += 0x7fffu + ((x >> 16) & 1u);   // RNE (finite inputs)
    return (ushort)(x >> 16);
}
static __device__ __forceinline__ float bf2f(ushort u) { return __uint_as_float((uint)u << 16); }

// ---------------- degree histogram ----------------
__global__ void count_kernel(const int* __restrict__ dst, int* __restrict__ cnt, int E) {
    int e = blockIdx.x * blockDim.x + threadIdx.x;
    if (e < E) atomicAdd(&cnt[dst[e]], 1);
}

__global__ void inv_kernel(const int* __restrict__ cnt, float* __restrict__ inv, int N) {
    int n = blockIdx.x * blockDim.x + threadIdx.x;
    if (n < N) inv[n] = 1.0f / fmaxf((float)cnt[n], 1.0f);
}

// ---------------- multi-block scan ----------------
__global__ __launch_bounds__(256) void blocksum_kernel(const int* __restrict__ cnt,
                                                       int* __restrict__ bsum, int N) {
    int base = blockIdx.x * 1024 + threadIdx.x * 4;
    int s = 0;
    if (base + 3 < N) {
        int4 v = *reinterpret_cast<const int4*>(cnt + base);
        s = v.x + v.y + v.z + v.w;
    } else {
        for (int i = 0; i < 4; ++i) if (base + i < N) s += cnt[base + i];
    }
    for (int off = 32; off > 0; off >>= 1) s += __shfl_down(s, off, 64);
    __shared__ int wsum[4];
    if ((threadIdx.x & 63) == 0) wsum[threadIdx.x >> 6] = s;
    __syncthreads();
    if (threadIdx.x == 0) bsum[blockIdx.x] = wsum[0] + wsum[1] + wsum[2] + wsum[3];
}

__global__ void scansum_kernel(int* __restrict__ bsum, int* __restrict__ rowptr, int NB, int N) {
    int t = threadIdx.x;
    int v = (t < NB) ? bsum[t] : 0;
    for (int off = 1; off < 64; off <<= 1) {
        int u = __shfl_up(v, off, 64);
        if (t >= off) v += u;
    }
    if (t < NB) bsum[t] = v;
    if (t == NB - 1) rowptr[N] = v;
}

__global__ __launch_bounds__(256) void writeptr_kernel(const int* __restrict__ cnt,
                                                       const int* __restrict__ bsum,
                                                       int* __restrict__ rowptr, int N) {
    const int b = blockIdx.x;
    const int base = b * 1024 + threadIdx.x * 4;
    int vals[4];
#pragma unroll
    for (int i = 0; i < 4; ++i) vals[i] = (base + i < N) ? cnt[base + i] : 0;
    int s = vals[0] + vals[1] + vals[2] + vals[3];

    const int lane = threadIdx.x & 63, w = threadIdx.x >> 6;
    int incl = s;
    for (int off = 1; off < 64; off <<= 1) {
        int u = __shfl_up(incl, off, 64);
        if (lane >= off) incl += u;
    }
    __shared__ int wsum[4];
    if (lane == 63) wsum[w] = incl;
    __syncthreads();
    int excl = (b == 0) ? 0 : bsum[b - 1];
    for (int i = 0; i < w; ++i) excl += wsum[i];
    excl += incl - s;

    int run = excl;
#pragma unroll
    for (int i = 0; i < 4; ++i) {
        if (base + i < N) { rowptr[base + i] = run; run += vals[i]; }
    }
}

// ---------------- CSR fill ----------------
__global__ void fill_kernel(const int* __restrict__ src, const int* __restrict__ dst,
                            const int* __restrict__ rowptr, int* __restrict__ fill,
                            int* __restrict__ col, int E) {
    int e = blockIdx.x * blockDim.x + threadIdx.x;
    if (e < E) {
        int d = dst[e];
        int pos = atomicAdd(&fill[d], 1);
        col[rowptr[d] + pos] = src[e];
    }
}

// ---------------- weight split: wt_hi/wt_lo[col][k] bf16, k in [0,256) ----------------
__global__ void cast_w_split(const float* __restrict__ Wl, const float* __restrict__ Wr,
                             ushort* __restrict__ wth, ushort* __restrict__ wtl) {
    int i = blockIdx.x * blockDim.x + threadIdx.x;   // 0..32767
    int colg = i >> 8, k = i & 255;
    float v = (k < 128) ? Wl[k * 128 + colg] : Wr[(k - 128) * 128 + colg];
    ushort h = f2bf(v);
    wth[i] = h;
    wtl[i] = f2bf(v - bf2f(h));
}

// ---------------- CSR mean-aggregate (f32, 2 half-wave chains, 2-unroll) ----------------
__global__ __launch_bounds__(256) void aggregate_kernel(
    const float* __restrict__ in, const int* __restrict__ rowptr,
    const int* __restrict__ col, const float* __restrict__ inv,
    float* __restrict__ agg, int N) {
    int wid = (blockIdx.x * 256 + threadIdx.x) >> 6;
    int lane = threadIdx.x & 63;
    if (wid >= N) return;
    int lo = rowptr[wid], hi = rowptr[wid + 1];
    const int h = lane >> 5;
    const int cb = (lane & 31) * 4;        // f32 col base; 32 lanes x 16B = 512B row
    float a0 = 0.f, a1 = 0.f, a2 = 0.f, a3 = 0.f;
    int e = lo + h;
    for (; e + 2 < hi; e += 4) {
        int s0 = col[e], s1 = col[e + 2];
        float4 v0 = *reinterpret_cast<const float4*>(in + (size_t)s0 * D + cb);
        float4 v1 = *reinterpret_cast<const float4*>(in + (size_t)s1 * D + cb);
        a0 += v0.x + v1.x; a1 += v0.y + v1.y;
        a2 += v0.z + v1.z; a3 += v0.w + v1.w;
    }
    for (; e < hi; e += 2) {
        int s0 = col[e];
        float4 v0 = *reinterpret_cast<const float4*>(in + (size_t)s0 * D + cb);
        a0 += v0.x; a1 += v0.y; a2 += v0.z; a3 += v0.w;
    }
    a0 += __shfl_xor(a0, 32, 64);
    a1 += __shfl_xor(a1, 32, 64);
    a2 += __shfl_xor(a2, 32, 64);
    a3 += __shfl_xor(a3, 32, 64);
    if (h == 0) {
        float s = inv[wid];
        float4 o;
        o.x = a0 * s; o.y = a1 * s; o.z = a2 * s; o.w = a3 * s;
        *reinterpret_cast<float4*>(agg + (size_t)wid * D + cb) = o;
    }
}

// ---------------- split-bf16 MFMA transform: out = relu([agg|in]@Wt^T + bl), all f32 I/O ----------------
// 64 rows/block, 4 waves; A split to hi/lo bf16 planes in LDS (XOR-swizzled);
// C = Ah@Wh + Al@Wh + Ah@Wl  (error ~2^-17, f32-class). Safe for out==in (per-block rows).
__global__ __launch_bounds__(256) void transform_mfma(
    const float* __restrict__ agg, const float* __restrict__ in,
    const ushort* __restrict__ wth, const ushort* __restrict__ wtl,  // [128 col][256 k]
    const float* __restrict__ bl,
    float* __restrict__ outp, int N) {
    __shared__ ushort Ah[64 * 256];   // 32 KB
    __shared__ ushort Al[64 * 256];   // 32 KB
    const int tid = threadIdx.x;
    const int row0 = blockIdx.x * 64;

    // stage: thread -> (row r = tid>>2, quarter q = tid&3); quarter = 64 f32 cols
    {
        const int r = tid >> 2, q = tid & 3;
        const int n = row0 + r;
        const float* srcrow = (q < 2) ? (agg + (size_t)n * D + q * 64)
                                      : (in + (size_t)n * D + (q - 2) * 64);
#pragma unroll
        for (int c8 = 0; c8 < 8; ++c8) {         // 8 f32 per iter
            float4 v0 = make_float4(0.f, 0.f, 0.f, 0.f);
            float4 v1 = make_float4(0.f, 0.f, 0.f, 0.f);
            if (n < N) {
                v0 = *reinterpret_cast<const float4*>(srcrow + c8 * 8);
                v1 = *reinterpret_cast<const float4*>(srcrow + c8 * 8 + 4);
            }
            ushort h0 = f2bf(v0.x), h1 = f2bf(v0.y), h2 = f2bf(v0.z), h3 = f2bf(v0.w);
            ushort h4 = f2bf(v1.x), h5 = f2bf(v1.y), h6 = f2bf(v1.z), h7 = f2bf(v1.w);
            uint4 hv, lv;
            hv.x = (uint)h0 | ((uint)h1 << 16);
            hv.y = (uint)h2 | ((uint)h3 << 16);
            hv.z = (uint)h4 | ((uint)h5 << 16);
            hv.w = (uint)h6 | ((uint)h7 << 16);
            lv.x = (uint)f2bf(v0.x - bf2f(h0)) | ((uint)f2bf(v0.y - bf2f(h1)) << 16);
            lv.y = (uint)f2bf(v0.z - bf2f(h2)) | ((uint)f2bf(v0.w - bf2f(h3)) << 16);
            lv.z = (uint)f2bf(v1.x - bf2f(h4)) | ((uint)f2bf(v1.y - bf2f(h5)) << 16);
            lv.w = (uint)f2bf(v1.z - bf2f(h6)) | ((uint)f2bf(v1.w - bf2f(h7)) << 16);
            int byteoff = r * 512 + q * 128 + c8 * 16;
            byteoff ^= (r & 7) << 4;
            *reinterpret_cast<uint4*>(reinterpret_cast<char*>(Ah) + byteoff) = hv;
            *reinterpret_cast<uint4*>(reinterpret_cast<char*>(Al) + byteoff) = lv;
        }
    }
    __syncthreads();

    const int w = tid >> 6;
    const int lane = tid & 63;
    const int lrow = lane & 15;   // A row within wave tile / D col
    const int lk = lane >> 4;     // 0..3

    bf16x8 ah[8], al[8];
    const int arow = w * 16 + lrow;
#pragma unroll
    for (int kb = 0; kb < 8; ++kb) {
        int byteoff = arow * 512 + (kb * 32 + lk * 8) * 2;
        byteoff ^= (arow & 7) << 4;
        ah[kb] = *reinterpret_cast<const bf16x8*>(reinterpret_cast<const char*>(Ah) + byteoff);
        al[kb] = *reinterpret_cast<const bf16x8*>(reinterpret_cast<const char*>(Al) + byteoff);
    }

    f32x4 acc[8] = {};
#pragma unroll
    for (int ct = 0; ct < 8; ++ct) {
        const ushort* bph = wth + (ct * 16 + lrow) * 256 + lk * 8;
        const ushort* bpl = wtl + (ct * 16 + lrow) * 256 + lk * 8;
#pragma unroll
        for (int kb = 0; kb < 8; ++kb) {
            bf16x8 bh = *reinterpret_cast<const bf16x8*>(bph + kb * 32);
            bf16x8 blo = *reinterpret_cast<const bf16x8*>(bpl + kb * 32);
            acc[ct] = __builtin_amdgcn_mfma_f32_16x16x32_bf16(ah[kb], bh, acc[ct], 0, 0, 0);
            acc[ct] = __builtin_amdgcn_mfma_f32_16x16x32_bf16(al[kb], bh, acc[ct], 0, 0, 0);
            acc[ct] = __builtin_amdgcn_mfma_f32_16x16x32_bf16(ah[kb], blo, acc[ct], 0, 0, 0);
        }
    }

    // D: col = lane&15 (per ct tile), row = (lane>>4)*4 + r
#pragma unroll
    for (int ct = 0; ct < 8; ++ct) {
        const int colg = ct * 16 + lrow;
        const float bias = bl[colg];
#pragma unroll
        for (int r = 0; r < 4; ++r) {
            int rowg = row0 + w * 16 + lk * 4 + r;
            if (rowg < N) {
                outp[(size_t)rowg * D + colg] = fmaxf(acc[ct][r] + bias, 0.0f);
            }
        }
    }
}

// ---------------- parallel pool ----------------
__global__ __launch_bounds__(256) void pool_kernel(
    const float* __restrict__ h, const int* __restrict__ batch,
    float* __restrict__ gsum, int N) {
    const int c = (threadIdx.x & 63) * 2;
    const int r = threadIdx.x >> 6;
    const int n0 = blockIdx.x * POOL_NODES;
    const int n1 = min(n0 + POOL_NODES, N);
    int gid = -1;
    float ax = 0.0f, ay = 0.0f;
    for (int n = n0 + r; n < n1; n += 4) {
        int b = batch[n];
        if (b != gid) {
            if (gid >= 0) {
                atomicAdd(&gsum[gid * D + c], ax);
                atomicAdd(&gsum[gid * D + c + 1], ay);
            }
            gid = b; ax = 0.0f; ay = 0.0f;
        }
        float2 v = *reinterpret_cast<const float2*>(h + (size_t)n * D + c);
        ax += v.x; ay += v.y;
    }
    if (gid >= 0) {
        atomicAdd(&gsum[gid * D + c], ax);
        atomicAdd(&gsum[gid * D + c + 1], ay);
    }
}

// ---------------- head ----------------
__global__ __launch_bounds__(128) void head_kernel(
    const float* __restrict__ gsum, const int* __restrict__ batch, int N,
    const float* __restrict__ W1, const float* __restrict__ b1,
    const float* __restrict__ W2, const float* __restrict__ b2,
    float* __restrict__ out) {
    __shared__ float gl[128];
    __shared__ float tl[128];
    __shared__ float lg[10];
    __shared__ float red[2];
    const int b = blockIdx.x, j = threadIdx.x;

    int lo = 0, r = N;
    while (lo < r) { int m = (lo + r) >> 1; if (batch[m] < b) lo = m + 1; else r = m; }
    int hi = lo; r = N;
    while (hi < r) { int m = (hi + r) >> 1; if (batch[m] < b + 1) hi = m + 1; else r = m; }

    float c = fmaxf((float)(hi - lo), 1.0f);
    gl[j] = gsum[b * D + j] / c;
    __syncthreads();

    float t = b1[j];
    for (int k = 0; k < 128; ++k) t += gl[k] * W1[k * 128 + j];
    tl[j] = fmaxf(t, 0.0f);
    __syncthreads();

    if (j < 10) {
        float acc = b2[j];
        for (int k = 0; k < 128; ++k) acc += tl[k] * W2[k * 10 + j];
        lg[j] = acc;
    }
    __syncthreads();

    if (j == 0) {
        float m = lg[0];
        for (int q = 1; q < 10; ++q) m = fmaxf(m, lg[q]);
        float s = 0.0f;
        for (int q = 0; q < 10; ++q) s += expf(lg[q] - m);
        red[0] = m;
        red[1] = logf(s);
    }
    __syncthreads();

    if (j < 10) out[b * 10 + j] = lg[j] - red[0] - red[1];
}

extern "C" void kernel_launch(void* const* d_in, const int* in_sizes, int n_in,
                              void* d_out, int out_size, void* d_ws, size_t ws_size,
                              hipStream_t stream) {
    const float* x    = (const float*)d_in[0];
    const int*   ei   = (const int*)d_in[1];
    const int*   src  = ei;
    const int*   dst  = ei + NE;
    const int*   batch = (const int*)d_in[2];
    const float* Wl1 = (const float*)d_in[3];
    const float* bl1 = (const float*)d_in[4];
    const float* Wr1 = (const float*)d_in[5];
    const float* Wl2 = (const float*)d_in[6];
    const float* bl2 = (const float*)d_in[7];
    const float* Wr2 = (const float*)d_in[8];
    const float* Wl3 = (const float*)d_in[9];
    const float* bl3 = (const float*)d_in[10];
    const float* Wr3 = (const float*)d_in[11];
    const float* W1  = (const float*)d_in[12];
    const float* b1  = (const float*)d_in[13];
    const float* W2  = (const float*)d_in[14];
    const float* b2  = (const float*)d_in[15];
    float* out = (float*)d_out;

    char* p = (char*)d_ws;
    float* agg  = (float*)p; p += 25600000;
    float* hA   = (float*)p; p += 25600000;
    ushort* wth = (ushort*)p; p += 3 * 65536;   // 3 layers x 128x256 bf16 hi
    ushort* wtl = (ushort*)p; p += 3 * 65536;   // lo
    float* inv  = (float*)p; p += 200000;
    float* gsum = (float*)p; p += 65536;
    int* cnt    = (int*)p;   p += 200000;
    int* rowptr = (int*)p;   p += 200016;
    int* fillp  = (int*)p;   p += 200000;
    int* colb   = (int*)p;   p += 3200000;
    int* bsum   = (int*)p;   p += 256;
    // ~56 MB total

    // ---- CSR build ----
    hipMemsetAsync(cnt, 0, (size_t)NN * 4, stream);
    hipMemsetAsync(fillp, 0, (size_t)NN * 4, stream);
    hipMemsetAsync(gsum, 0, (size_t)NG * D * 4, stream);
    count_kernel<<<(NE + 255) / 256, 256, 0, stream>>>(dst, cnt, NE);
    inv_kernel<<<(NN + 255) / 256, 256, 0, stream>>>(cnt, inv, NN);
    blocksum_kernel<<<SCAN_NB, 256, 0, stream>>>(cnt, bsum, NN);
    scansum_kernel<<<1, 64, 0, stream>>>(bsum, rowptr, SCAN_NB, NN);
    writeptr_kernel<<<SCAN_NB, 256, 0, stream>>>(cnt, bsum, rowptr, NN);
    fill_kernel<<<(NE + 255) / 256, 256, 0, stream>>>(src, dst, rowptr, fillp, colb, NE);

    // ---- weight splits ----
    cast_w_split<<<128, 256, 0, stream>>>(Wl1, Wr1, wth, wtl);
    cast_w_split<<<128, 256, 0, stream>>>(Wl2, Wr2, wth + 32768, wtl + 32768);
    cast_w_split<<<128, 256, 0, stream>>>(Wl3, Wr3, wth + 65536, wtl + 65536);

    const int agg_blocks = (NN * 64) / 256 + 1;
    const int trans_blocks = (NN + 63) / 64;

    aggregate_kernel<<<agg_blocks, 256, 0, stream>>>(x, rowptr, colb, inv, agg, NN);
    transform_mfma<<<trans_blocks, 256, 0, stream>>>(agg, x, wth, wtl, bl1, hA, NN);
    aggregate_kernel<<<agg_blocks, 256, 0, stream>>>(hA, rowptr, colb, inv, agg, NN);
    transform_mfma<<<trans_blocks, 256, 0, stream>>>(agg, hA, wth + 32768, wtl + 32768, bl2, hA, NN);
    aggregate_kernel<<<agg_blocks, 256, 0, stream>>>(hA, rowptr, colb, inv, agg, NN);
    transform_mfma<<<trans_blocks, 256, 0, stream>>>(agg, hA, wth + 65536, wtl + 65536, bl3, hA, NN);

    pool_kernel<<<(NN + POOL_NODES - 1) / POOL_NODES, 256, 0, stream>>>(hA, batch, gsum, NN);
    head_kernel<<<NG, 128, 0, stream>>>(gsum, batch, NN, W1, b1, W2, b2, out);
}

// Round 10
// 502.153 us; speedup vs baseline: 1.0686x; 1.0686x over previous
//
#include <hip/hip_runtime.h>

#define NN 50000
#define NE 800000
#define D 128
#define NG 128
#define POOL_NODES 128
#define SCAN_NB ((NN + 1023) / 1024)   // 49

typedef __attribute__((ext_vector_type(8))) short bf16x8;
typedef __attribute__((ext_vector_type(4))) float f32x4;

static __device__ __forceinline__ ushort f2bf(float f) {
    uint x = __float_as_uint(f);
    x += 0x7fffu + ((x >> 16) & 1u);   // RNE (finite inputs)
    return (ushort)(x >> 16);
}
static __device__ __forceinline__ float bf2f(ushort u) { return __uint_as_float((uint)u << 16); }

// ---------------- degree histogram ----------------
__global__ void count_kernel(const int* __restrict__ dst, int* __restrict__ cnt, int E) {
    int e = blockIdx.x * blockDim.x + threadIdx.x;
    if (e < E) atomicAdd(&cnt[dst[e]], 1);
}

__global__ void inv_kernel(const int* __restrict__ cnt, float* __restrict__ inv, int N) {
    int n = blockIdx.x * blockDim.x + threadIdx.x;
    if (n < N) inv[n] = 1.0f / fmaxf((float)cnt[n], 1.0f);
}

// ---------------- multi-block scan ----------------
__global__ __launch_bounds__(256) void blocksum_kernel(const int* __restrict__ cnt,
                                                       int* __restrict__ bsum, int N) {
    int base = blockIdx.x * 1024 + threadIdx.x * 4;
    int s = 0;
    if (base + 3 < N) {
        int4 v = *reinterpret_cast<const int4*>(cnt + base);
        s = v.x + v.y + v.z + v.w;
    } else {
        for (int i = 0; i < 4; ++i) if (base + i < N) s += cnt[base + i];
    }
    for (int off = 32; off > 0; off >>= 1) s += __shfl_down(s, off, 64);
    __shared__ int wsum[4];
    if ((threadIdx.x & 63) == 0) wsum[threadIdx.x >> 6] = s;
    __syncthreads();
    if (threadIdx.x == 0) bsum[blockIdx.x] = wsum[0] + wsum[1] + wsum[2] + wsum[3];
}

__global__ void scansum_kernel(int* __restrict__ bsum, int* __restrict__ rowptr, int NB, int N) {
    int t = threadIdx.x;
    int v = (t < NB) ? bsum[t] : 0;
    for (int off = 1; off < 64; off <<= 1) {
        int u = __shfl_up(v, off, 64);
        if (t >= off) v += u;
    }
    if (t < NB) bsum[t] = v;
    if (t == NB - 1) rowptr[N] = v;
}

__global__ __launch_bounds__(256) void writeptr_kernel(const int* __restrict__ cnt,
                                                       const int* __restrict__ bsum,
                                                       int* __restrict__ rowptr, int N) {
    const int b = blockIdx.x;
    const int base = b * 1024 + threadIdx.x * 4;
    int vals[4];
#pragma unroll
    for (int i = 0; i < 4; ++i) vals[i] = (base + i < N) ? cnt[base + i] : 0;
    int s = vals[0] + vals[1] + vals[2] + vals[3];

    const int lane = threadIdx.x & 63, w = threadIdx.x >> 6;
    int incl = s;
    for (int off = 1; off < 64; off <<= 1) {
        int u = __shfl_up(incl, off, 64);
        if (lane >= off) incl += u;
    }
    __shared__ int wsum[4];
    if (lane == 63) wsum[w] = incl;
    __syncthreads();
    int excl = (b == 0) ? 0 : bsum[b - 1];
    for (int i = 0; i < w; ++i) excl += wsum[i];
    excl += incl - s;

    int run = excl;
#pragma unroll
    for (int i = 0; i < 4; ++i) {
        if (base + i < N) { rowptr[base + i] = run; run += vals[i]; }
    }
}

// ---------------- CSR fill ----------------
__global__ void fill_kernel(const int* __restrict__ src, const int* __restrict__ dst,
                            const int* __restrict__ rowptr, int* __restrict__ fill,
                            int* __restrict__ col, int E) {
    int e = blockIdx.x * blockDim.x + threadIdx.x;
    if (e < E) {
        int d = dst[e];
        int pos = atomicAdd(&fill[d], 1);
        col[rowptr[d] + pos] = src[e];
    }
}

// ---------------- weight split: wt_hi/wt_lo[col][k] bf16, k in [0,256) ----------------
__global__ void cast_w_split(const float* __restrict__ Wl, const float* __restrict__ Wr,
                             ushort* __restrict__ wth, ushort* __restrict__ wtl) {
    int i = blockIdx.x * blockDim.x + threadIdx.x;   // 0..32767
    int colg = i >> 8, k = i & 255;
    float v = (k < 128) ? Wl[k * 128 + colg] : Wr[(k - 128) * 128 + colg];
    ushort h = f2bf(v);
    wth[i] = h;
    wtl[i] = f2bf(v - bf2f(h));
}

// ---------------- CSR mean-aggregate (f32, 2 half-wave chains, 2-unroll) ----------------
__global__ __launch_bounds__(256) void aggregate_kernel(
    const float* __restrict__ in, const int* __restrict__ rowptr,
    const int* __restrict__ col, const float* __restrict__ inv,
    float* __restrict__ agg, int N) {
    int wid = (blockIdx.x * 256 + threadIdx.x) >> 6;
    int lane = threadIdx.x & 63;
    if (wid >= N) return;
    int lo = rowptr[wid], hi = rowptr[wid + 1];
    const int h = lane >> 5;
    const int cb = (lane & 31) * 4;
    float a0 = 0.f, a1 = 0.f, a2 = 0.f, a3 = 0.f;
    int e = lo + h;
    for (; e + 2 < hi; e += 4) {
        int s0 = col[e], s1 = col[e + 2];
        float4 v0 = *reinterpret_cast<const float4*>(in + (size_t)s0 * D + cb);
        float4 v1 = *reinterpret_cast<const float4*>(in + (size_t)s1 * D + cb);
        a0 += v0.x + v1.x; a1 += v0.y + v1.y;
        a2 += v0.z + v1.z; a3 += v0.w + v1.w;
    }
    for (; e < hi; e += 2) {
        int s0 = col[e];
        float4 v0 = *reinterpret_cast<const float4*>(in + (size_t)s0 * D + cb);
        a0 += v0.x; a1 += v0.y; a2 += v0.z; a3 += v0.w;
    }
    a0 += __shfl_xor(a0, 32, 64);
    a1 += __shfl_xor(a1, 32, 64);
    a2 += __shfl_xor(a2, 32, 64);
    a3 += __shfl_xor(a3, 32, 64);
    if (h == 0) {
        float s = inv[wid];
        float4 o;
        o.x = a0 * s; o.y = a1 * s; o.z = a2 * s; o.w = a3 * s;
        *reinterpret_cast<float4*>(agg + (size_t)wid * D + cb) = o;
    }
}

// ---------------- split-bf16 MFMA transform, LDS-free ----------------
// out = relu([agg|in] @ Wt^T + bl); A fragments loaded per-lane directly from
// global (32B each), split to hi/lo bf16 in registers. C = Ah@Wh + Al@Wh + Ah@Wl.
// 64 rows/block, 4 waves; each wave: 16 rows x 128 cols, K=256.
// No LDS -> no sync, no bank conflicts, occupancy VGPR-limited (LB 256,4 -> <=128 VGPR).
__global__ __launch_bounds__(256, 4) void transform_mfma(
    const float* __restrict__ agg, const float* __restrict__ in,
    const ushort* __restrict__ wth, const ushort* __restrict__ wtl,  // [128 col][256 k]
    const float* __restrict__ bl,
    float* __restrict__ outp, int N) {
    const int tid = threadIdx.x;
    const int w = tid >> 6;
    const int lane = tid & 63;
    const int lrow = lane & 15;   // A row in wave tile / D col
    const int lk = lane >> 4;     // 0..3 (8-elem k chunk within 32-k block)
    const int row0 = blockIdx.x * 64;

    const int arow = row0 + w * 16 + lrow;
    const int arc = (arow < N) ? arow : (N - 1);   // clamp: garbage rows never stored
    const float* aprow = agg + (size_t)arc * D + lk * 8;
    const float* inrow = in + (size_t)arc * D + lk * 8;

    f32x4 acc[8] = {};

#pragma unroll
    for (int kb = 0; kb < 8; ++kb) {
        const float* srcp = (kb < 4) ? (aprow + kb * 32) : (inrow + (kb - 4) * 32);
        float4 v0 = *reinterpret_cast<const float4*>(srcp);
        float4 v1 = *reinterpret_cast<const float4*>(srcp + 4);

        ushort h0 = f2bf(v0.x), h1 = f2bf(v0.y), h2 = f2bf(v0.z), h3 = f2bf(v0.w);
        ushort h4 = f2bf(v1.x), h5 = f2bf(v1.y), h6 = f2bf(v1.z), h7 = f2bf(v1.w);
        bf16x8 ah, al;
        ah[0] = (short)h0; ah[1] = (short)h1; ah[2] = (short)h2; ah[3] = (short)h3;
        ah[4] = (short)h4; ah[5] = (short)h5; ah[6] = (short)h6; ah[7] = (short)h7;
        al[0] = (short)f2bf(v0.x - bf2f(h0)); al[1] = (short)f2bf(v0.y - bf2f(h1));
        al[2] = (short)f2bf(v0.z - bf2f(h2)); al[3] = (short)f2bf(v0.w - bf2f(h3));
        al[4] = (short)f2bf(v1.x - bf2f(h4)); al[5] = (short)f2bf(v1.y - bf2f(h5));
        al[6] = (short)f2bf(v1.z - bf2f(h6)); al[7] = (short)f2bf(v1.w - bf2f(h7));

#pragma unroll
        for (int ct = 0; ct < 8; ++ct) {
            const ushort* bph = wth + (ct * 16 + lrow) * 256 + kb * 32 + lk * 8;
            const ushort* bpl = wtl + (ct * 16 + lrow) * 256 + kb * 32 + lk * 8;
            bf16x8 bh = *reinterpret_cast<const bf16x8*>(bph);
            bf16x8 blo = *reinterpret_cast<const bf16x8*>(bpl);
            acc[ct] = __builtin_amdgcn_mfma_f32_16x16x32_bf16(ah, bh, acc[ct], 0, 0, 0);
            acc[ct] = __builtin_amdgcn_mfma_f32_16x16x32_bf16(al, bh, acc[ct], 0, 0, 0);
            acc[ct] = __builtin_amdgcn_mfma_f32_16x16x32_bf16(ah, blo, acc[ct], 0, 0, 0);
        }
    }

    // D layout: col = lane&15 (per ct tile), row = (lane>>4)*4 + reg
#pragma unroll
    for (int ct = 0; ct < 8; ++ct) {
        const int colg = ct * 16 + lrow;
        const float bias = bl[colg];
#pragma unroll
        for (int r = 0; r < 4; ++r) {
            int rowg = row0 + w * 16 + lk * 4 + r;
            if (rowg < N) {
                outp[(size_t)rowg * D + colg] = fmaxf(acc[ct][r] + bias, 0.0f);
            }
        }
    }
}

// ---------------- parallel pool ----------------
__global__ __launch_bounds__(256) void pool_kernel(
    const float* __restrict__ h, const int* __restrict__ batch,
    float* __restrict__ gsum, int N) {
    const int c = (threadIdx.x & 63) * 2;
    const int r = threadIdx.x >> 6;
    const int n0 = blockIdx.x * POOL_NODES;
    const int n1 = min(n0 + POOL_NODES, N);
    int gid = -1;
    float ax = 0.0f, ay = 0.0f;
    for (int n = n0 + r; n < n1; n += 4) {
        int b = batch[n];
        if (b != gid) {
            if (gid >= 0) {
                atomicAdd(&gsum[gid * D + c], ax);
                atomicAdd(&gsum[gid * D + c + 1], ay);
            }
            gid = b; ax = 0.0f; ay = 0.0f;
        }
        float2 v = *reinterpret_cast<const float2*>(h + (size_t)n * D + c);
        ax += v.x; ay += v.y;
    }
    if (gid >= 0) {
        atomicAdd(&gsum[gid * D + c], ax);
        atomicAdd(&gsum[gid * D + c + 1], ay);
    }
}

// ---------------- head ----------------
__global__ __launch_bounds__(128) void head_kernel(
    const float* __restrict__ gsum, const int* __restrict__ batch, int N,
    const float* __restrict__ W1, const float* __restrict__ b1,
    const float* __restrict__ W2, const float* __restrict__ b2,
    float* __restrict__ out) {
    __shared__ float gl[128];
    __shared__ float tl[128];
    __shared__ float lg[10];
    __shared__ float red[2];
    const int b = blockIdx.x, j = threadIdx.x;

    int lo = 0, r = N;
    while (lo < r) { int m = (lo + r) >> 1; if (batch[m] < b) lo = m + 1; else r = m; }
    int hi = lo; r = N;
    while (hi < r) { int m = (hi + r) >> 1; if (batch[m] < b + 1) hi = m + 1; else r = m; }

    float c = fmaxf((float)(hi - lo), 1.0f);
    gl[j] = gsum[b * D + j] / c;
    __syncthreads();

    float t = b1[j];
    for (int k = 0; k < 128; ++k) t += gl[k] * W1[k * 128 + j];
    tl[j] = fmaxf(t, 0.0f);
    __syncthreads();

    if (j < 10) {
        float acc = b2[j];
        for (int k = 0; k < 128; ++k) acc += tl[k] * W2[k * 10 + j];
        lg[j] = acc;
    }
    __syncthreads();

    if (j == 0) {
        float m = lg[0];
        for (int q = 1; q < 10; ++q) m = fmaxf(m, lg[q]);
        float s = 0.0f;
        for (int q = 0; q < 10; ++q) s += expf(lg[q] - m);
        red[0] = m;
        red[1] = logf(s);
    }
    __syncthreads();

    if (j < 10) out[b * 10 + j] = lg[j] - red[0] - red[1];
}

extern "C" void kernel_launch(void* const* d_in, const int* in_sizes, int n_in,
                              void* d_out, int out_size, void* d_ws, size_t ws_size,
                              hipStream_t stream) {
    const float* x    = (const float*)d_in[0];
    const int*   ei   = (const int*)d_in[1];
    const int*   src  = ei;
    const int*   dst  = ei + NE;
    const int*   batch = (const int*)d_in[2];
    const float* Wl1 = (const float*)d_in[3];
    const float* bl1 = (const float*)d_in[4];
    const float* Wr1 = (const float*)d_in[5];
    const float* Wl2 = (const float*)d_in[6];
    const float* bl2 = (const float*)d_in[7];
    const float* Wr2 = (const float*)d_in[8];
    const float* Wl3 = (const float*)d_in[9];
    const float* bl3 = (const float*)d_in[10];
    const float* Wr3 = (const float*)d_in[11];
    const float* W1  = (const float*)d_in[12];
    const float* b1  = (const float*)d_in[13];
    const float* W2  = (const float*)d_in[14];
    const float* b2  = (const float*)d_in[15];
    float* out = (float*)d_out;

    char* p = (char*)d_ws;
    float* agg  = (float*)p; p += 25600000;
    float* hA   = (float*)p; p += 25600000;
    ushort* wth = (ushort*)p; p += 3 * 65536;   // 3 layers x 128x256 bf16 hi
    ushort* wtl = (ushort*)p; p += 3 * 65536;   // lo
    float* inv  = (float*)p; p += 200000;
    float* gsum = (float*)p; p += 65536;
    int* cnt    = (int*)p;   p += 200000;
    int* rowptr = (int*)p;   p += 200016;
    int* fillp  = (int*)p;   p += 200000;
    int* colb   = (int*)p;   p += 3200000;
    int* bsum   = (int*)p;   p += 256;
    // ~56 MB total

    // ---- CSR build ----
    hipMemsetAsync(cnt, 0, (size_t)NN * 4, stream);
    hipMemsetAsync(fillp, 0, (size_t)NN * 4, stream);
    hipMemsetAsync(gsum, 0, (size_t)NG * D * 4, stream);
    count_kernel<<<(NE + 255) / 256, 256, 0, stream>>>(dst, cnt, NE);
    inv_kernel<<<(NN + 255) / 256, 256, 0, stream>>>(cnt, inv, NN);
    blocksum_kernel<<<SCAN_NB, 256, 0, stream>>>(cnt, bsum, NN);
    scansum_kernel<<<1, 64, 0, stream>>>(bsum, rowptr, SCAN_NB, NN);
    writeptr_kernel<<<SCAN_NB, 256, 0, stream>>>(cnt, bsum, rowptr, NN);
    fill_kernel<<<(NE + 255) / 256, 256, 0, stream>>>(src, dst, rowptr, fillp, colb, NE);

    // ---- weight splits ----
    cast_w_split<<<128, 256, 0, stream>>>(Wl1, Wr1, wth, wtl);
    cast_w_split<<<128, 256, 0, stream>>>(Wl2, Wr2, wth + 32768, wtl + 32768);
    cast_w_split<<<128, 256, 0, stream>>>(Wl3, Wr3, wth + 65536, wtl + 65536);

    const int agg_blocks = (NN * 64) / 256 + 1;
    const int trans_blocks = (NN + 63) / 64;

    aggregate_kernel<<<agg_blocks, 256, 0, stream>>>(x, rowptr, colb, inv, agg, NN);
    transform_mfma<<<trans_blocks, 256, 0, stream>>>(agg, x, wth, wtl, bl1, hA, NN);
    aggregate_kernel<<<agg_blocks, 256, 0, stream>>>(hA, rowptr, colb, inv, agg, NN);
    transform_mfma<<<trans_blocks, 256, 0, stream>>>(agg, hA, wth + 32768, wtl + 32768, bl2, hA, NN);
    aggregate_kernel<<<agg_blocks, 256, 0, stream>>>(hA, rowptr, colb, inv, agg, NN);
    transform_mfma<<<trans_blocks, 256, 0, stream>>>(agg, hA, wth + 65536, wtl + 65536, bl3, hA, NN);

    pool_kernel<<<(NN + POOL_NODES - 1) / POOL_NODES, 256, 0, stream>>>(hA, batch, gsum, NN);
    head_kernel<<<NG, 128, 0, stream>>>(gsum, batch, NN, W1, b1, W2, b2, out);
}

// Round 11
// 405.894 us; speedup vs baseline: 1.3220x; 1.2372x over previous
//
#include <hip/hip_runtime.h>

#define NN 50000
#define NE 800000
#define D 128
#define NG 128
#define POOL_NODES 128
#define SCAN_NB ((NN + 1023) / 1024)   // 49

typedef __attribute__((ext_vector_type(8))) short bf16x8;
typedef __attribute__((ext_vector_type(4))) float f32x4;

static __device__ __forceinline__ ushort f2bf(float f) {
    uint x = __float_as_uint(f);
    x += 0x7fffu + ((x >> 16) & 1u);   // RNE
    return (ushort)(x >> 16);
}
static __device__ __forceinline__ float bf2f(ushort u) { return __uint_as_float((uint)u << 16); }
static __device__ __forceinline__ float blo16(uint u) { return __uint_as_float(u << 16); }
static __device__ __forceinline__ float bhi16(uint u) { return __uint_as_float(u & 0xffff0000u); }

// ---------------- degree histogram ----------------
__global__ void count_kernel(const int* __restrict__ dst, int* __restrict__ cnt, int E) {
    int e = blockIdx.x * blockDim.x + threadIdx.x;
    if (e < E) atomicAdd(&cnt[dst[e]], 1);
}

// ---------------- multi-block scan ----------------
__global__ __launch_bounds__(256) void blocksum_kernel(const int* __restrict__ cnt,
                                                       int* __restrict__ bsum, int N) {
    int base = blockIdx.x * 1024 + threadIdx.x * 4;
    int s = 0;
    if (base + 3 < N) {
        int4 v = *reinterpret_cast<const int4*>(cnt + base);
        s = v.x + v.y + v.z + v.w;
    } else {
        for (int i = 0; i < 4; ++i) if (base + i < N) s += cnt[base + i];
    }
    for (int off = 32; off > 0; off >>= 1) s += __shfl_down(s, off, 64);
    __shared__ int wsum[4];
    if ((threadIdx.x & 63) == 0) wsum[threadIdx.x >> 6] = s;
    __syncthreads();
    if (threadIdx.x == 0) bsum[blockIdx.x] = wsum[0] + wsum[1] + wsum[2] + wsum[3];
}

__global__ void scansum_kernel(int* __restrict__ bsum, int* __restrict__ rowptr, int NB, int N) {
    int t = threadIdx.x;
    int v = (t < NB) ? bsum[t] : 0;
    for (int off = 1; off < 64; off <<= 1) {
        int u = __shfl_up(v, off, 64);
        if (t >= off) v += u;
    }
    if (t < NB) bsum[t] = v;
    if (t == NB - 1) rowptr[N] = v;
}

__global__ __launch_bounds__(256) void writeptr_kernel(const int* __restrict__ cnt,
                                                       const int* __restrict__ bsum,
                                                       int* __restrict__ rowptr, int N) {
    const int b = blockIdx.x;
    const int base = b * 1024 + threadIdx.x * 4;
    int vals[4];
#pragma unroll
    for (int i = 0; i < 4; ++i) vals[i] = (base + i < N) ? cnt[base + i] : 0;
    int s = vals[0] + vals[1] + vals[2] + vals[3];

    const int lane = threadIdx.x & 63, w = threadIdx.x >> 6;
    int incl = s;
    for (int off = 1; off < 64; off <<= 1) {
        int u = __shfl_up(incl, off, 64);
        if (lane >= off) incl += u;
    }
    __shared__ int wsum[4];
    if (lane == 63) wsum[w] = incl;
    __syncthreads();
    int excl = (b == 0) ? 0 : bsum[b - 1];
    for (int i = 0; i < w; ++i) excl += wsum[i];
    excl += incl - s;

    int run = excl;
#pragma unroll
    for (int i = 0; i < 4; ++i) {
        if (base + i < N) { rowptr[base + i] = run; run += vals[i]; }
    }
}

// ---------------- CSR fill (fillp buffer = reused cnt, re-zeroed) ----------------
__global__ void fill_kernel(const int* __restrict__ src, const int* __restrict__ dst,
                            const int* __restrict__ rowptr, int* __restrict__ fillp,
                            int* __restrict__ col, int E) {
    int e = blockIdx.x * blockDim.x + threadIdx.x;
    if (e < E) {
        int d = dst[e];
        int pos = atomicAdd(&fillp[d], 1);
        col[rowptr[d] + pos] = src[e];
    }
}

// ---------------- fused weight split, 3 layers: wt[col][k] hi/lo bf16 ----------------
__global__ void cast_w3(const float* __restrict__ Wl1, const float* __restrict__ Wr1,
                        const float* __restrict__ Wl2, const float* __restrict__ Wr2,
                        const float* __restrict__ Wl3, const float* __restrict__ Wr3,
                        ushort* __restrict__ wth, ushort* __restrict__ wtl) {
    int i = blockIdx.x * blockDim.x + threadIdx.x;   // 0..3*32768
    int layer = i >> 15, j = i & 32767;
    int colg = j >> 8, k = j & 255;
    const float* Wl = (layer == 0) ? Wl1 : ((layer == 1) ? Wl2 : Wl3);
    const float* Wr = (layer == 0) ? Wr1 : ((layer == 1) ? Wr2 : Wr3);
    float v = (k < 128) ? Wl[k * 128 + colg] : Wr[(k - 128) * 128 + colg];
    ushort h = f2bf(v);
    wth[i] = h;
    wtl[i] = f2bf(v - bf2f(h));
}

// ---------------- x -> interleaved hi/lo planes fx[N][256] bf16 ----------------
__global__ void cast_x(const float* __restrict__ x, ushort* __restrict__ fx) {
    int i = blockIdx.x * blockDim.x + threadIdx.x;   // NN*32
    if (i >= NN * 32) return;
    int n = i >> 5, g = i & 31;
    float4 v = *reinterpret_cast<const float4*>(x + (size_t)n * D + g * 4);
    ushort h0 = f2bf(v.x), h1 = f2bf(v.y), h2 = f2bf(v.z), h3 = f2bf(v.w);
    uint2 hh, ll;
    hh.x = (uint)h0 | ((uint)h1 << 16);
    hh.y = (uint)h2 | ((uint)h3 << 16);
    ll.x = (uint)f2bf(v.x - bf2f(h0)) | ((uint)f2bf(v.y - bf2f(h1)) << 16);
    ll.y = (uint)f2bf(v.z - bf2f(h2)) | ((uint)f2bf(v.w - bf2f(h3)) << 16);
    char* row = (char*)fx + (size_t)n * 512;
    *reinterpret_cast<uint2*>(row + g * 8) = hh;
    *reinterpret_cast<uint2*>(row + 256 + g * 8) = ll;
}

// ---------------- CSR mean-aggregate on interleaved planes ----------------
// full wave per node: lanes 0-31 accumulate hi plane, 32-63 lo plane; shfl(32) combine.
__global__ __launch_bounds__(256) void aggregate_i(
    const ushort* __restrict__ fx, const int* __restrict__ rowptr,
    const int* __restrict__ col, ushort* __restrict__ aggx, int N) {
    int wid = (blockIdx.x * 256 + threadIdx.x) >> 6;
    int lane = threadIdx.x & 63;
    if (wid >= N) return;
    int lo = rowptr[wid], hi = rowptr[wid + 1];
    const int boff = (lane >> 5) * 256 + (lane & 31) * 8;
    float a0 = 0.f, a1 = 0.f, a2 = 0.f, a3 = 0.f;
    int e = lo;
    for (; e + 3 < hi; e += 4) {
        int s0 = col[e], s1 = col[e + 1], s2 = col[e + 2], s3 = col[e + 3];
        uint2 v0 = *reinterpret_cast<const uint2*>((const char*)fx + (size_t)s0 * 512 + boff);
        uint2 v1 = *reinterpret_cast<const uint2*>((const char*)fx + (size_t)s1 * 512 + boff);
        uint2 v2 = *reinterpret_cast<const uint2*>((const char*)fx + (size_t)s2 * 512 + boff);
        uint2 v3 = *reinterpret_cast<const uint2*>((const char*)fx + (size_t)s3 * 512 + boff);
        a0 += blo16(v0.x) + blo16(v1.x) + blo16(v2.x) + blo16(v3.x);
        a1 += bhi16(v0.x) + bhi16(v1.x) + bhi16(v2.x) + bhi16(v3.x);
        a2 += blo16(v0.y) + blo16(v1.y) + blo16(v2.y) + blo16(v3.y);
        a3 += bhi16(v0.y) + bhi16(v1.y) + bhi16(v2.y) + bhi16(v3.y);
    }
    for (; e < hi; ++e) {
        int s0 = col[e];
        uint2 v = *reinterpret_cast<const uint2*>((const char*)fx + (size_t)s0 * 512 + boff);
        a0 += blo16(v.x); a1 += bhi16(v.x); a2 += blo16(v.y); a3 += bhi16(v.y);
    }
    a0 += __shfl_xor(a0, 32, 64);
    a1 += __shfl_xor(a1, 32, 64);
    a2 += __shfl_xor(a2, 32, 64);
    a3 += __shfl_xor(a3, 32, 64);
    if (lane < 32) {
        float inv = 1.0f / fmaxf((float)(hi - lo), 1.0f);
        float w0 = a0 * inv, w1 = a1 * inv, w2 = a2 * inv, w3 = a3 * inv;
        ushort h0 = f2bf(w0), h1 = f2bf(w1), h2 = f2bf(w2), h3 = f2bf(w3);
        uint2 hh, ll;
        hh.x = (uint)h0 | ((uint)h1 << 16);
        hh.y = (uint)h2 | ((uint)h3 << 16);
        ll.x = (uint)f2bf(w0 - bf2f(h0)) | ((uint)f2bf(w1 - bf2f(h1)) << 16);
        ll.y = (uint)f2bf(w2 - bf2f(h2)) | ((uint)f2bf(w3 - bf2f(h3)) << 16);
        char* orow = (char*)aggx + (size_t)wid * 512;
        int cb8 = (lane & 31) * 8;
        *reinterpret_cast<uint2*>(orow + cb8) = hh;
        *reinterpret_cast<uint2*>(orow + 256 + cb8) = ll;
    }
}

// ---------------- B-resident split-bf16 MFMA transform, in-place on fx ----------------
// h = relu([agg|root] @ W^T + b); root rows snapshot in swizzled LDS (in-place safety);
// B hi/lo (2 col-tiles x K=256) resident in 128 VGPRs; 8 M-tiles of 16 rows per block.
__global__ __launch_bounds__(256, 2) void transform_i(
    const ushort* __restrict__ aggx, ushort* __restrict__ fx,
    const ushort* __restrict__ wth, const ushort* __restrict__ wtl,  // [128 col][256 k]
    const float* __restrict__ bl, int N) {
    __shared__ char R[128 * 512];   // 64 KB root snapshot, XOR-swizzled 16B chunks
    const int tid = threadIdx.x;
    const int row0 = blockIdx.x * 128;

    {   // stage: thread -> (row = tid>>1, half = tid&1), 16 x 16B chunks
        const int r = tid >> 1;
        const int half = (tid & 1) * 256;
        const int n = row0 + r;
        const char* src = (const char*)fx + (size_t)n * 512 + half;
#pragma unroll
        for (int c = 0; c < 16; ++c) {
            uint4 v = make_uint4(0, 0, 0, 0);
            if (n < N) v = *reinterpret_cast<const uint4*>(src + c * 16);
            int byte = r * 512 + half + c * 16;
            *reinterpret_cast<uint4*>(R + (byte ^ ((r & 7) << 4))) = v;
        }
    }
    __syncthreads();

    const int w = tid >> 6, lane = tid & 63;
    const int lrow = lane & 15, lk = lane >> 4;
    const int wc = w * 32;

    bf16x8 bh[2][8], blv[2][8];
#pragma unroll
    for (int ct = 0; ct < 2; ++ct) {
        const ushort* ph = wth + (wc + ct * 16 + lrow) * 256 + lk * 8;
        const ushort* pl = wtl + (wc + ct * 16 + lrow) * 256 + lk * 8;
#pragma unroll
        for (int kb = 0; kb < 8; ++kb) {
            bh[ct][kb] = *reinterpret_cast<const bf16x8*>(ph + kb * 32);
            blv[ct][kb] = *reinterpret_cast<const bf16x8*>(pl + kb * 32);
        }
    }
    const float bias0 = bl[wc + lrow], bias1 = bl[wc + 16 + lrow];

#pragma unroll
    for (int mt = 0; mt < 8; ++mt) {
        const int lr = mt * 16 + lrow;
        const int arow = min(row0 + lr, N - 1);
        const char* ap = (const char*)aggx + (size_t)arow * 512;
        f32x4 acc0 = {0.f, 0.f, 0.f, 0.f}, acc1 = {0.f, 0.f, 0.f, 0.f};
#pragma unroll
        for (int kb = 0; kb < 8; ++kb) {
            bf16x8 ah, al;
            if (kb < 4) {   // agg half of K
                ah = *reinterpret_cast<const bf16x8*>(ap + kb * 64 + lk * 16);
                al = *reinterpret_cast<const bf16x8*>(ap + 256 + kb * 64 + lk * 16);
            } else {        // root half of K from LDS snapshot
                int byte = lr * 512 + (kb - 4) * 64 + lk * 16;
                ah = *reinterpret_cast<const bf16x8*>(R + (byte ^ ((lr & 7) << 4)));
                int byte2 = byte + 256;
                al = *reinterpret_cast<const bf16x8*>(R + (byte2 ^ ((lr & 7) << 4)));
            }
            acc0 = __builtin_amdgcn_mfma_f32_16x16x32_bf16(ah, bh[0][kb], acc0, 0, 0, 0);
            acc0 = __builtin_amdgcn_mfma_f32_16x16x32_bf16(al, bh[0][kb], acc0, 0, 0, 0);
            acc0 = __builtin_amdgcn_mfma_f32_16x16x32_bf16(ah, blv[0][kb], acc0, 0, 0, 0);
            acc1 = __builtin_amdgcn_mfma_f32_16x16x32_bf16(ah, bh[1][kb], acc1, 0, 0, 0);
            acc1 = __builtin_amdgcn_mfma_f32_16x16x32_bf16(al, bh[1][kb], acc1, 0, 0, 0);
            acc1 = __builtin_amdgcn_mfma_f32_16x16x32_bf16(ah, blv[1][kb], acc1, 0, 0, 0);
        }
        // epilogue (D: col = lane&15 per tile, row = lk*4 + r) — writes own rows only
#pragma unroll
        for (int r = 0; r < 4; ++r) {
            int rowg = row0 + mt * 16 + lk * 4 + r;
            if (rowg < N) {
                char* orow = (char*)fx + (size_t)rowg * 512;
                float v0 = fmaxf(acc0[r] + bias0, 0.f);
                ushort h0 = f2bf(v0);
                *reinterpret_cast<ushort*>(orow + (wc + lrow) * 2) = h0;
                *reinterpret_cast<ushort*>(orow + 256 + (wc + lrow) * 2) = f2bf(v0 - bf2f(h0));
                float v1 = fmaxf(acc1[r] + bias1, 0.f);
                ushort h1 = f2bf(v1);
                *reinterpret_cast<ushort*>(orow + (wc + 16 + lrow) * 2) = h1;
                *reinterpret_cast<ushort*>(orow + 256 + (wc + 16 + lrow) * 2) = f2bf(v1 - bf2f(h1));
            }
        }
    }
}

// ---------------- pool on interleaved planes ----------------
__global__ __launch_bounds__(256) void pool_i(
    const ushort* __restrict__ fx, const int* __restrict__ batch,
    float* __restrict__ gsum, int N) {
    const int lane = threadIdx.x & 63;
    const int wv = threadIdx.x >> 6;
    const int boff = (lane >> 5) * 256 + (lane & 31) * 8;
    const int cb = (lane & 31) * 4;
    const int n0 = blockIdx.x * POOL_NODES;
    const int n1 = min(n0 + POOL_NODES, N);
    int gid = -1;
    float a0 = 0.f, a1 = 0.f, a2 = 0.f, a3 = 0.f;
    for (int n = n0 + wv; n < n1; n += 4) {
        int b = batch[n];
        if (b != gid) {   // wave-uniform branch (same n sequence across the wave)
            if (gid >= 0) {
                a0 += __shfl_xor(a0, 32, 64); a1 += __shfl_xor(a1, 32, 64);
                a2 += __shfl_xor(a2, 32, 64); a3 += __shfl_xor(a3, 32, 64);
                if (lane < 32) {
                    atomicAdd(&gsum[gid * D + cb + 0], a0);
                    atomicAdd(&gsum[gid * D + cb + 1], a1);
                    atomicAdd(&gsum[gid * D + cb + 2], a2);
                    atomicAdd(&gsum[gid * D + cb + 3], a3);
                }
            }
            gid = b; a0 = a1 = a2 = a3 = 0.f;
        }
        uint2 v = *reinterpret_cast<const uint2*>((const char*)fx + (size_t)n * 512 + boff);
        a0 += blo16(v.x); a1 += bhi16(v.x); a2 += blo16(v.y); a3 += bhi16(v.y);
    }
    if (gid >= 0) {
        a0 += __shfl_xor(a0, 32, 64); a1 += __shfl_xor(a1, 32, 64);
        a2 += __shfl_xor(a2, 32, 64); a3 += __shfl_xor(a3, 32, 64);
        if (lane < 32) {
            atomicAdd(&gsum[gid * D + cb + 0], a0);
            atomicAdd(&gsum[gid * D + cb + 1], a1);
            atomicAdd(&gsum[gid * D + cb + 2], a2);
            atomicAdd(&gsum[gid * D + cb + 3], a3);
        }
    }
}

// ---------------- head ----------------
__global__ __launch_bounds__(128) void head_kernel(
    const float* __restrict__ gsum, const int* __restrict__ batch, int N,
    const float* __restrict__ W1, const float* __restrict__ b1,
    const float* __restrict__ W2, const float* __restrict__ b2,
    float* __restrict__ out) {
    __shared__ float gl[128];
    __shared__ float tl[128];
    __shared__ float lg[10];
    __shared__ float red[2];
    const int b = blockIdx.x, j = threadIdx.x;

    int lo = 0, r = N;
    while (lo < r) { int m = (lo + r) >> 1; if (batch[m] < b) lo = m + 1; else r = m; }
    int hi = lo; r = N;
    while (hi < r) { int m = (hi + r) >> 1; if (batch[m] < b + 1) hi = m + 1; else r = m; }

    float c = fmaxf((float)(hi - lo), 1.0f);
    gl[j] = gsum[b * D + j] / c;
    __syncthreads();

    float t = b1[j];
    for (int k = 0; k < 128; ++k) t += gl[k] * W1[k * 128 + j];
    tl[j] = fmaxf(t, 0.0f);
    __syncthreads();

    if (j < 10) {
        float acc = b2[j];
        for (int k = 0; k < 128; ++k) acc += tl[k] * W2[k * 10 + j];
        lg[j] = acc;
    }
    __syncthreads();

    if (j == 0) {
        float m = lg[0];
        for (int q = 1; q < 10; ++q) m = fmaxf(m, lg[q]);
        float s = 0.0f;
        for (int q = 0; q < 10; ++q) s += expf(lg[q] - m);
        red[0] = m;
        red[1] = logf(s);
    }
    __syncthreads();

    if (j < 10) out[b * 10 + j] = lg[j] - red[0] - red[1];
}

extern "C" void kernel_launch(void* const* d_in, const int* in_sizes, int n_in,
                              void* d_out, int out_size, void* d_ws, size_t ws_size,
                              hipStream_t stream) {
    const float* x    = (const float*)d_in[0];
    const int*   ei   = (const int*)d_in[1];
    const int*   src  = ei;
    const int*   dst  = ei + NE;
    const int*   batch = (const int*)d_in[2];
    const float* Wl1 = (const float*)d_in[3];
    const float* bl1 = (const float*)d_in[4];
    const float* Wr1 = (const float*)d_in[5];
    const float* Wl2 = (const float*)d_in[6];
    const float* bl2 = (const float*)d_in[7];
    const float* Wr2 = (const float*)d_in[8];
    const float* Wl3 = (const float*)d_in[9];
    const float* bl3 = (const float*)d_in[10];
    const float* Wr3 = (const float*)d_in[11];
    const float* W1  = (const float*)d_in[12];
    const float* b1  = (const float*)d_in[13];
    const float* W2  = (const float*)d_in[14];
    const float* b2  = (const float*)d_in[15];
    float* out = (float*)d_out;

    char* p = (char*)d_ws;
    ushort* fx   = (ushort*)p; p += 25600000;   // [NN][256] interleaved hi/lo (x, then h in place)
    ushort* aggx = (ushort*)p; p += 25600000;   // [NN][256] interleaved agg
    ushort* wth  = (ushort*)p; p += 196608;     // 3 x [128][256] hi
    ushort* wtl  = (ushort*)p; p += 196608;     // lo
    float*  gsum = (float*)p;  p += 65536;
    int* cnt     = (int*)p;    p += 200000;     // also reused as fill cursor
    int* rowptr  = (int*)p;    p += 200016;
    int* colb    = (int*)p;    p += 3200000;
    int* bsum    = (int*)p;    p += 256;
    // ~55.3 MB total (well under proven workspace)

    // ---- CSR build ----
    hipMemsetAsync(cnt, 0, (size_t)NN * 4, stream);
    hipMemsetAsync(gsum, 0, (size_t)NG * D * 4, stream);
    count_kernel<<<(NE + 255) / 256, 256, 0, stream>>>(dst, cnt, NE);
    blocksum_kernel<<<SCAN_NB, 256, 0, stream>>>(cnt, bsum, NN);
    scansum_kernel<<<1, 64, 0, stream>>>(bsum, rowptr, SCAN_NB, NN);
    writeptr_kernel<<<SCAN_NB, 256, 0, stream>>>(cnt, bsum, rowptr, NN);
    hipMemsetAsync(cnt, 0, (size_t)NN * 4, stream);          // reuse as fill cursor
    fill_kernel<<<(NE + 255) / 256, 256, 0, stream>>>(src, dst, rowptr, cnt, colb, NE);

    // ---- precision prep ----
    cast_w3<<<384, 256, 0, stream>>>(Wl1, Wr1, Wl2, Wr2, Wl3, Wr3, wth, wtl);
    cast_x<<<(NN * 32 + 255) / 256, 256, 0, stream>>>(x, fx);

    const int agg_blocks = (NN * 64 + 255) / 256;   // one wave per node
    const int trans_blocks = (NN + 127) / 128;

    for (int L = 0; L < 3; ++L) {
        const float* blv = (L == 0) ? bl1 : ((L == 1) ? bl2 : bl3);
        aggregate_i<<<agg_blocks, 256, 0, stream>>>(fx, rowptr, colb, aggx, NN);
        transform_i<<<trans_blocks, 256, 0, stream>>>(aggx, fx, wth + L * 32768, wtl + L * 32768, blv, NN);
    }

    pool_i<<<(NN + POOL_NODES - 1) / POOL_NODES, 256, 0, stream>>>(fx, batch, gsum, NN);
    head_kernel<<<NG, 128, 0, stream>>>(gsum, batch, NN, W1, b1, W2, b2, out);
}